// Round 12
// baseline (135.195 us; speedup 1.0000x reference)
//
#include <hip/hip_runtime.h>

// ---------------------------------------------------------------------------
// VisualContrastiveLoss on MI355X
// loss = C + mean_i log(Z_i) - mean_i sim[i, lab_i],  C = 1/0.07
//   Z_i = sum_j exp(sim_ij - C)   (fixed shift: dots bounded by 1)
//   sim = (f f^T)/0.07, f = row-normalized visual_feat
// R12: barrier-free K-loop. A (128 rows x full K) staged once into LDS
//     (one __syncthreads for the whole kernel); B fragments loaded DIRECTLY
//     from global (L2-resident fQ) as 2x int4 per frag -- the f8f6f4 B-operand
//     layout is a plain strided gather, no LDS transpose needed. This removes
//     the per-kk stage->barrier->compute->barrier structure (m97 plateau:
//     vmcnt(0) drain at every barrier) entirely. R11 lessons kept: 3-kernel
//     structure (fused tail's device fence cost ~37us), zero-conflict h()
//     granule layout for A, unroll-1 on jt/kk (unroller-induced spill).
// ---------------------------------------------------------------------------

typedef int i32x8 __attribute__((ext_vector_type(8)));
typedef float f32x4 __attribute__((ext_vector_type(4)));

#define B_N 8192
#define D_K 512
#define ROWB 512  // bytes per fp8 row
#define INVT 14.285714285714286f
// (1/0.07) * log2(e)
#define SCALE_LOG2 20.609929155556622f

static __device__ __forceinline__ void load16_to_lds(const void* g, void* l) {
  __builtin_amdgcn_global_load_lds(
      (const __attribute__((address_space(1))) unsigned int*)g,
      (__attribute__((address_space(3))) unsigned int*)l, 16, 0, 0);
}

// ---- K1: 4 waves/block, one wave per row; normalize fp32 -> fp8 e4m3 --------
// Also zeroes Z (ws is poisoned before every launch).
__global__ __launch_bounds__(256)
void norm_kernel(const float* __restrict__ x,
                 unsigned char* __restrict__ fQ,
                 float* __restrict__ Z) {
  const int row = blockIdx.x * 4 + (threadIdx.x >> 6);
  const int lane = threadIdx.x & 63;
  const float4* xr = (const float4*)(x + (size_t)row * D_K);
  float4 a = xr[2 * lane];
  float4 b = xr[2 * lane + 1];
  float s = a.x * a.x + a.y * a.y + a.z * a.z + a.w * a.w +
            b.x * b.x + b.y * b.y + b.z * b.z + b.w * b.w;
#pragma unroll
  for (int off = 1; off < 64; off <<= 1) s += __shfl_xor(s, off);
  const float inv = 1.0f / fmaxf(sqrtf(s), 1e-12f);
  int lo = 0, hi = 0;
  lo = __builtin_amdgcn_cvt_pk_fp8_f32(a.x * inv, a.y * inv, lo, false);
  lo = __builtin_amdgcn_cvt_pk_fp8_f32(a.z * inv, a.w * inv, lo, true);
  hi = __builtin_amdgcn_cvt_pk_fp8_f32(b.x * inv, b.y * inv, hi, false);
  hi = __builtin_amdgcn_cvt_pk_fp8_f32(b.z * inv, b.w * inv, hi, true);
  int2 p; p.x = lo; p.y = hi;
  ((int2*)(fQ + (size_t)row * ROWB))[lane] = p;
  if (lane == 0) Z[row] = 0.0f;
}

// ---- K2: fused fp8 similarity + partial softmax-denominator -----------------
// grid (64, 8): blockIdx.x -> 128-row tile, blockIdx.y -> 1024-col j-range
// (8 jt of 128 cols). 4 waves 2x2; wave owns 64x64 C via 4x4 frags of
// 16x16x128 MX-fp8 MFMA (scale=1).
// A: staged once to LDS (4 chunk-planes, h() granule layout, zero conflicts);
// B: loaded per-fragment straight from global/L2 (rows J0+n*16+fr, bytes
//    k0+32q / +16) -- no staging, no barriers in the K-loop.
__global__ __launch_bounds__(256, 2)
void sim_kernel(const unsigned char* __restrict__ fQ,
                float* __restrict__ Z, float* __restrict__ T01,
                float* __restrict__ D) {
  __shared__ unsigned char ldsA[4][128 * 128];  // 64 KB: full K, 4 chunk-planes

  const int tid = threadIdx.x;
  const int lane = tid & 63;
  const int w = tid >> 6;
  const int wm = w & 1;       // wave row strip (0/1) -> rows wm*64..
  const int wn = w >> 1;      // wave col strip (0/1) -> cols wn*64..
  const int bx = blockIdx.x, by = blockIdx.y;
  const int I0 = bx * 128;
  const int Jbase = by * 1024;

  // staging lane geometry: 8 rows x 8 slots(16B) per instruction.
  // slot b of row a sources global granule h(b^a), h(u)=2(u&3)+(u>>2).
  const int srow = lane >> 3;                 // 0..7
  const int sb = lane & 7;                    // dest slot
  const int su = sb ^ srow;
  const int sg = 2 * (su & 3) + (su >> 2);    // source granule
  const size_t sOff = (size_t)srow * ROWB + sg * 16;  // bytes

  // fragment-read lane geometry
  const int fr = lane & 15;   // M/N index within 16
  const int q = lane >> 4;    // quad -> k chunk of 32B
  const int swz = fr & 7;     // row&7 of the frag row

  // A frag base (LDS, swizzled slots); B frag base (global, direct)
  const int raRow = (wm * 64 + fr) * 128;
  const int off0 = (q ^ swz) * 16;        // slot holding granule 2q
  const int off1 = ((q + 4) ^ swz) * 16;  // slot holding granule 2q+1
  const unsigned char* bBase =
      fQ + (size_t)(Jbase + wn * 64 + fr) * ROWB + q * 32;

  // ---- stage A once: wave w stages rows w*32..+31, all 4 K-chunks ----------
#pragma unroll
  for (int kk = 0; kk < 4; ++kk) {
    const unsigned char* gA = fQ + (size_t)(I0 + w * 32) * ROWB + kk * 128 + sOff;
    unsigned char* lA = ldsA[kk] + (w * 32) * 128;
#pragma unroll
    for (int rr = 0; rr < 32; rr += 8)
      load16_to_lds(gA + (size_t)rr * ROWB, lA + rr * 128);
  }
  __syncthreads();  // the ONLY barrier in this kernel

  float Zp[4][4];
#pragma unroll
  for (int m = 0; m < 4; ++m)
#pragma unroll
    for (int r = 0; r < 4; ++r) Zp[m][r] = 0.0f;

#pragma unroll 1
  for (int jt = 0; jt < 8; ++jt) {
    const int J0 = Jbase + jt * 128;
    const unsigned char* bJt = bBase + (size_t)jt * 128 * ROWB;
    f32x4 acc[4][4];
#pragma unroll
    for (int m = 0; m < 4; ++m)
#pragma unroll
      for (int n = 0; n < 4; ++n) acc[m][n] = (f32x4){0.f, 0.f, 0.f, 0.f};

#pragma unroll 1
    for (int kk = 0; kk < 4; ++kk) {
      const int k0 = kk * 128;  // byte offset into row
      const unsigned char* raBase = ldsA[kk] + raRow;

      // B fragments straight from global (L2): rows n*16 apart, 2x16B each
      i32x8 bv[4];
#pragma unroll
      for (int n = 0; n < 4; ++n) {
        const unsigned char* bp = bJt + (size_t)n * 16 * ROWB + k0;
        int4 r0 = *(const int4*)(bp);
        int4 r1 = *(const int4*)(bp + 16);
        bv[n] = (i32x8){r0.x, r0.y, r0.z, r0.w, r1.x, r1.y, r1.z, r1.w};
      }
#pragma unroll
      for (int mh = 0; mh < 2; ++mh) {  // m-split: av[2] live, not av[4]
        i32x8 av[2];
#pragma unroll
        for (int m = 0; m < 2; ++m) {
          const unsigned char* ra = raBase + (mh * 2 + m) * 16 * 128;
          int4 r0 = *(const int4*)(ra + off0);
          int4 r1 = *(const int4*)(ra + off1);
          av[m] = (i32x8){r0.x, r0.y, r0.z, r0.w, r1.x, r1.y, r1.z, r1.w};
        }
#pragma unroll
        for (int m = 0; m < 2; ++m)
#pragma unroll
          for (int n = 0; n < 4; ++n)
            acc[mh * 2 + m][n] = __builtin_amdgcn_mfma_scale_f32_16x16x128_f8f6f4(
                av[m], bv[n], acc[mh * 2 + m][n], 0, 0, 0, 127, 0, 127);
      }
      // no barrier: A is static in LDS, B comes from global
    }

    // capture sim[:,0] and sim[:,1] (cols 0,1: j-tile 0, wn==0, n==0, fr<2)
    if (by == 0 && jt == 0 && wn == 0 && fr < 2) {
#pragma unroll
      for (int m = 0; m < 4; ++m)
#pragma unroll
        for (int r = 0; r < 4; ++r) {
          const int row = I0 + wm * 64 + m * 16 + q * 4 + r;
          T01[row * 2 + fr] = acc[m][0][r] * INVT;
        }
    }

    // capture the computed diagonal dot (for exact-diag correction)
    if (by == (bx >> 3) && jt == (bx & 7)) {
#pragma unroll
      for (int m = 0; m < 4; ++m)
#pragma unroll
        for (int n = 0; n < 4; ++n) {
          const int col = J0 + wn * 64 + n * 16 + fr;
#pragma unroll
          for (int r = 0; r < 4; ++r) {
            const int row = I0 + wm * 64 + m * 16 + q * 4 + r;
            if (row == col) D[row] = acc[m][n][r];
          }
        }
    }

    // Z partials: exp((dot-1)/T) summed over this wave's 64 cols
#pragma unroll
    for (int m = 0; m < 4; ++m)
#pragma unroll
      for (int n = 0; n < 4; ++n)
#pragma unroll
        for (int r = 0; r < 4; ++r)
          Zp[m][r] += exp2f((acc[m][n][r] - 1.0f) * SCALE_LOG2);
  }

  // reduce Zp across the 16 col-lanes (low 4 lane bits), then atomicAdd
#pragma unroll
  for (int m = 0; m < 4; ++m)
#pragma unroll
    for (int r = 0; r < 4; ++r) {
      float v = Zp[m][r];
      v += __shfl_xor(v, 1);
      v += __shfl_xor(v, 2);
      v += __shfl_xor(v, 4);
      v += __shfl_xor(v, 8);
      if (fr == 0) atomicAdd(&Z[I0 + wm * 64 + m * 16 + q * 4 + r], v);
    }
}

// ---- K3: labels + exact-diagonal fixup + final loss reduction ---------------
// 1024 threads, 8 rows each, all loads batched/independent.
__global__ __launch_bounds__(1024)
void finalize_kernel(const float* __restrict__ Z,
                     const float* __restrict__ T01,
                     const float* __restrict__ D,
                     const int* __restrict__ ids,
                     const int* __restrict__ anchor,
                     float* __restrict__ out) {
  __shared__ float red[1024];
  const int t = threadIdx.x;
  const int anchor_id = ids[anchor[0]];
  const int sameLast = (ids[B_N - 1] == anchor_id);
  const int samePrev = (ids[B_N - 2] == anchor_id);
  int i[8], id[8];
  float z[8], d[8], t0[8], t1[8];
#pragma unroll
  for (int u = 0; u < 8; ++u) {
    i[u] = u * 1024 + t;
    z[u] = Z[i[u]];
    d[u] = D[i[u]];
    t0[u] = T01[i[u] * 2 + 0];
    t1[u] = T01[i[u] * 2 + 1];
    id[u] = ids[i[u]];
  }
  float sum = 0.0f;
#pragma unroll
  for (int u = 0; u < 8; ++u) {
    const int same_i = (id[u] == anchor_id);
    const int lab =
        (i[u] < B_N - 1) ? (same_i & sameLast) : (sameLast & samePrev);
    const float tt = lab ? t1[u] : t0[u];
    // replace quantized diag contribution with the exact value exp(0)=1
    const float Zc = z[u] - exp2f((d[u] - 1.0f) * SCALE_LOG2) + 1.0f;
    sum += tt - (INVT + logf(Zc));
  }
  red[t] = sum;
  __syncthreads();
  for (int off = 512; off > 0; off >>= 1) {
    if (t < off) red[t] += red[t + off];
    __syncthreads();
  }
  if (t == 0) out[0] = -red[0] / (float)B_N;
}

// ---------------------------------------------------------------------------
extern "C" void kernel_launch(void* const* d_in, const int* in_sizes, int n_in,
                              void* d_out, int out_size, void* d_ws, size_t ws_size,
                              hipStream_t stream) {
  const float* x = (const float*)d_in[0];
  const int* ids = (const int*)d_in[1];
  const int* anchor = (const int*)d_in[2];
  float* out = (float*)d_out;

  unsigned char* fQ = (unsigned char*)d_ws;                    // 4 MB fp8
  float* Z = (float*)((char*)d_ws + (size_t)B_N * ROWB);       // 32 KB
  float* T01 = Z + B_N;                                        // 64 KB
  float* D = T01 + 2 * B_N;                                    // 32 KB

  norm_kernel<<<B_N / 4, 256, 0, stream>>>(x, fQ, Z);
  sim_kernel<<<dim3(64, 8), 256, 0, stream>>>(fQ, Z, T01, D);
  finalize_kernel<<<1, 1024, 0, stream>>>(Z, T01, D, ids, anchor, out);
}

// Round 13
// 113.039 us; speedup vs baseline: 1.1960x; 1.1960x over previous
//
#include <hip/hip_runtime.h>

// ---------------------------------------------------------------------------
// VisualContrastiveLoss on MI355X
// loss = C + mean_i log(Z_i) - mean_i sim[i, lab_i],  C = 1/0.07
//   Z_i = sum_j exp(sim_ij - C)   (fixed shift: dots bounded by 1)
//   sim = (f f^T)/0.07, f = row-normalized visual_feat
// R13: R11 structure (best: 54.2us) + VALU diet:
//     (a) raw v_exp_f32 via __builtin_amdgcn_exp2f for the Z partials --
//         exp2f without -ffast-math lowers to the ocml wrapper (~7 instrs);
//         our arg range [-45,+3] is exact on the HW instruction.
//     (b) frag i32x8 built via union of int4 halves so ds_read_b128 lands
//         directly in MFMA operand regs (no vector-construction movs).
//     Kept: 3-kernel structure (fused-tail fence cost ~37us, R10), A staged
//     once (4 chunk-planes, h() zero-conflict granule layout, R9/R10),
//     B staged per kk via global_load_lds, unroll-1 on jt/kk (R6).
//     R12 lesson: direct-global B frags = scattered 16B/lane gather,
//     +19us -- B must go through LDS staging.
// ---------------------------------------------------------------------------

typedef int i32x8 __attribute__((ext_vector_type(8)));
typedef float f32x4 __attribute__((ext_vector_type(4)));

#define B_N 8192
#define D_K 512
#define ROWB 512  // bytes per fp8 row
#define INVT 14.285714285714286f
// (1/0.07) * log2(e)
#define SCALE_LOG2 20.609929155556622f

#if defined(__has_builtin) && __has_builtin(__builtin_amdgcn_exp2f)
#define FAST_EXP2(x) __builtin_amdgcn_exp2f(x)
#else
#define FAST_EXP2(x) exp2f(x)
#endif

union FragU {
  int4 h[2];
  i32x8 v;
};

static __device__ __forceinline__ void load16_to_lds(const void* g, void* l) {
  __builtin_amdgcn_global_load_lds(
      (const __attribute__((address_space(1))) unsigned int*)g,
      (__attribute__((address_space(3))) unsigned int*)l, 16, 0, 0);
}

// ---- K1: 4 waves/block, one wave per row; normalize fp32 -> fp8 e4m3 --------
// Also zeroes Z (ws is poisoned before every launch).
__global__ __launch_bounds__(256)
void norm_kernel(const float* __restrict__ x,
                 unsigned char* __restrict__ fQ,
                 float* __restrict__ Z) {
  const int row = blockIdx.x * 4 + (threadIdx.x >> 6);
  const int lane = threadIdx.x & 63;
  const float4* xr = (const float4*)(x + (size_t)row * D_K);
  float4 a = xr[2 * lane];
  float4 b = xr[2 * lane + 1];
  float s = a.x * a.x + a.y * a.y + a.z * a.z + a.w * a.w +
            b.x * b.x + b.y * b.y + b.z * b.z + b.w * b.w;
#pragma unroll
  for (int off = 1; off < 64; off <<= 1) s += __shfl_xor(s, off);
  const float inv = 1.0f / fmaxf(sqrtf(s), 1e-12f);
  int lo = 0, hi = 0;
  lo = __builtin_amdgcn_cvt_pk_fp8_f32(a.x * inv, a.y * inv, lo, false);
  lo = __builtin_amdgcn_cvt_pk_fp8_f32(a.z * inv, a.w * inv, lo, true);
  hi = __builtin_amdgcn_cvt_pk_fp8_f32(b.x * inv, b.y * inv, hi, false);
  hi = __builtin_amdgcn_cvt_pk_fp8_f32(b.z * inv, b.w * inv, hi, true);
  int2 p; p.x = lo; p.y = hi;
  ((int2*)(fQ + (size_t)row * ROWB))[lane] = p;
  if (lane == 0) Z[row] = 0.0f;
}

// ---- K2: fused fp8 similarity + partial softmax-denominator -----------------
// grid (64, 8): blockIdx.x -> 128-row tile, blockIdx.y -> 1024-col j-range
// (8 jt of 128 cols). 4 waves 2x2; wave owns 64x64 C via 4x4 frags of
// 16x16x128 MX-fp8 MFMA (scale=1). A (128 rows x full K) staged once into
// 4 chunk-planes of 16KB; B staged per kk (16KB). Granule layout per 128B
// chunk: slot s of row r holds global granule h(s^(r&7)), h(u)=2(u&3)+(u>>2);
// frag reads at slots (q)^swz,(q+4)^swz -> granules 2q,2q+1, zero conflicts.
__global__ __launch_bounds__(256, 2)
void sim_kernel(const unsigned char* __restrict__ fQ,
                float* __restrict__ Z, float* __restrict__ T01,
                float* __restrict__ D) {
  __shared__ unsigned char ldsA[4][128 * 128];  // 64 KB: full K, 4 chunk-planes
  __shared__ unsigned char ldsB[128 * 128];     // 16 KB

  const int tid = threadIdx.x;
  const int lane = tid & 63;
  const int w = tid >> 6;
  const int wm = w & 1;       // wave row strip (0/1) -> rows wm*64..
  const int wn = w >> 1;      // wave col strip (0/1) -> cols wn*64..
  const int bx = blockIdx.x, by = blockIdx.y;
  const int I0 = bx * 128;
  const int Jbase = by * 1024;

  // staging lane geometry: 8 rows x 8 slots(16B) per instruction.
  // slot b of row a sources global granule h(b^a), h(u)=2(u&3)+(u>>2).
  const int srow = lane >> 3;                 // 0..7
  const int sb = lane & 7;                    // dest slot
  const int su = sb ^ srow;
  const int sg = 2 * (su & 3) + (su >> 2);    // source granule
  const size_t sOff = (size_t)srow * ROWB + sg * 16;  // bytes

  // fragment-read lane geometry
  const int fr = lane & 15;   // M/N index within 16
  const int q = lane >> 4;    // quad -> k chunk of 32B
  const int swz = fr & 7;     // row&7 of the frag row

  // precomputed LDS frag base offsets (byte addresses)
  const int raRow = (wm * 64 + fr) * 128;
  const unsigned char* rbBase = ldsB + (wn * 64 + fr) * 128;
  const int off0 = (q ^ swz) * 16;        // slot holding granule 2q
  const int off1 = ((q + 4) ^ swz) * 16;  // slot holding granule 2q+1

  // ---- stage A once: wave w stages rows w*32..+31, all 4 K-chunks ----------
#pragma unroll
  for (int kk = 0; kk < 4; ++kk) {
    const unsigned char* gA = fQ + (size_t)(I0 + w * 32) * ROWB + kk * 128 + sOff;
    unsigned char* lA = ldsA[kk] + (w * 32) * 128;
#pragma unroll
    for (int rr = 0; rr < 32; rr += 8)
      load16_to_lds(gA + (size_t)rr * ROWB, lA + rr * 128);
  }
  // (first __syncthreads inside the kk loop below covers A readiness)

  float Zp[4][4];
#pragma unroll
  for (int m = 0; m < 4; ++m)
#pragma unroll
    for (int r = 0; r < 4; ++r) Zp[m][r] = 0.0f;

#pragma unroll 1
  for (int jt = 0; jt < 8; ++jt) {
    const int J0 = Jbase + jt * 128;
    f32x4 acc[4][4];
#pragma unroll
    for (int m = 0; m < 4; ++m)
#pragma unroll
      for (int n = 0; n < 4; ++n) acc[m][n] = (f32x4){0.f, 0.f, 0.f, 0.f};

#pragma unroll 1
    for (int kk = 0; kk < 4; ++kk) {
      const int k0 = kk * 128;  // byte offset into row
      {  // B: 128 rows, wave stages rows w*32..+31 (4 instrs)
        const unsigned char* gB = fQ + (size_t)(J0 + w * 32) * ROWB + k0 + sOff;
        unsigned char* lB = ldsB + (w * 32) * 128;
#pragma unroll
        for (int rr = 0; rr < 32; rr += 8)
          load16_to_lds(gB + (size_t)rr * ROWB, lB + rr * 128);
      }
      __syncthreads();

      const unsigned char* raBase = ldsA[kk] + raRow;
      i32x8 bv[4];
#pragma unroll
      for (int n = 0; n < 4; ++n) {
        const unsigned char* rb = rbBase + n * 16 * 128;
        FragU u;
        u.h[0] = *(const int4*)(rb + off0);
        u.h[1] = *(const int4*)(rb + off1);
        bv[n] = u.v;
      }
#pragma unroll
      for (int mh = 0; mh < 2; ++mh) {  // m-split: av[2] live, not av[4]
        i32x8 av[2];
#pragma unroll
        for (int m = 0; m < 2; ++m) {
          const unsigned char* ra = raBase + (mh * 2 + m) * 16 * 128;
          FragU u;
          u.h[0] = *(const int4*)(ra + off0);
          u.h[1] = *(const int4*)(ra + off1);
          av[m] = u.v;
        }
#pragma unroll
        for (int m = 0; m < 2; ++m)
#pragma unroll
          for (int n = 0; n < 4; ++n)
            acc[mh * 2 + m][n] = __builtin_amdgcn_mfma_scale_f32_16x16x128_f8f6f4(
                av[m], bv[n], acc[mh * 2 + m][n], 0, 0, 0, 127, 0, 127);
      }
      __syncthreads();
    }

    // capture sim[:,0] and sim[:,1] (cols 0,1: j-tile 0, wn==0, n==0, fr<2)
    if (by == 0 && jt == 0 && wn == 0 && fr < 2) {
#pragma unroll
      for (int m = 0; m < 4; ++m)
#pragma unroll
        for (int r = 0; r < 4; ++r) {
          const int row = I0 + wm * 64 + m * 16 + q * 4 + r;
          T01[row * 2 + fr] = acc[m][0][r] * INVT;
        }
    }

    // capture the computed diagonal dot (for exact-diag correction)
    if (by == (bx >> 3) && jt == (bx & 7)) {
#pragma unroll
      for (int m = 0; m < 4; ++m)
#pragma unroll
        for (int n = 0; n < 4; ++n) {
          const int col = J0 + wn * 64 + n * 16 + fr;
#pragma unroll
          for (int r = 0; r < 4; ++r) {
            const int row = I0 + wm * 64 + m * 16 + q * 4 + r;
            if (row == col) D[row] = acc[m][n][r];
          }
        }
    }

    // Z partials: exp((dot-1)/T) summed over this wave's 64 cols.
    // Raw v_exp_f32: arg range [-45,+3] -- exact on HW, no libm wrapper.
#pragma unroll
    for (int m = 0; m < 4; ++m)
#pragma unroll
      for (int n = 0; n < 4; ++n)
#pragma unroll
        for (int r = 0; r < 4; ++r)
          Zp[m][r] += FAST_EXP2((acc[m][n][r] - 1.0f) * SCALE_LOG2);
  }

  // reduce Zp across the 16 col-lanes (low 4 lane bits), then atomicAdd
#pragma unroll
  for (int m = 0; m < 4; ++m)
#pragma unroll
    for (int r = 0; r < 4; ++r) {
      float v = Zp[m][r];
      v += __shfl_xor(v, 1);
      v += __shfl_xor(v, 2);
      v += __shfl_xor(v, 4);
      v += __shfl_xor(v, 8);
      if (fr == 0) atomicAdd(&Z[I0 + wm * 64 + m * 16 + q * 4 + r], v);
    }
}

// ---- K3: labels + exact-diagonal fixup + final loss reduction ---------------
// 1024 threads, 8 rows each, all loads batched/independent.
__global__ __launch_bounds__(1024)
void finalize_kernel(const float* __restrict__ Z,
                     const float* __restrict__ T01,
                     const float* __restrict__ D,
                     const int* __restrict__ ids,
                     const int* __restrict__ anchor,
                     float* __restrict__ out) {
  __shared__ float red[1024];
  const int t = threadIdx.x;
  const int anchor_id = ids[anchor[0]];
  const int sameLast = (ids[B_N - 1] == anchor_id);
  const int samePrev = (ids[B_N - 2] == anchor_id);
  int i[8], id[8];
  float z[8], d[8], t0[8], t1[8];
#pragma unroll
  for (int u = 0; u < 8; ++u) {
    i[u] = u * 1024 + t;
    z[u] = Z[i[u]];
    d[u] = D[i[u]];
    t0[u] = T01[i[u] * 2 + 0];
    t1[u] = T01[i[u] * 2 + 1];
    id[u] = ids[i[u]];
  }
  float sum = 0.0f;
#pragma unroll
  for (int u = 0; u < 8; ++u) {
    const int same_i = (id[u] == anchor_id);
    const int lab =
        (i[u] < B_N - 1) ? (same_i & sameLast) : (sameLast & samePrev);
    const float tt = lab ? t1[u] : t0[u];
    // replace quantized diag contribution with the exact value exp(0)=1
    const float Zc = z[u] - FAST_EXP2((d[u] - 1.0f) * SCALE_LOG2) + 1.0f;
    sum += tt - (INVT + logf(Zc));
  }
  red[t] = sum;
  __syncthreads();
  for (int off = 512; off > 0; off >>= 1) {
    if (t < off) red[t] += red[t + off];
    __syncthreads();
  }
  if (t == 0) out[0] = -red[0] / (float)B_N;
}

// ---------------------------------------------------------------------------
extern "C" void kernel_launch(void* const* d_in, const int* in_sizes, int n_in,
                              void* d_out, int out_size, void* d_ws, size_t ws_size,
                              hipStream_t stream) {
  const float* x = (const float*)d_in[0];
  const int* ids = (const int*)d_in[1];
  const int* anchor = (const int*)d_in[2];
  float* out = (float*)d_out;

  unsigned char* fQ = (unsigned char*)d_ws;                    // 4 MB fp8
  float* Z = (float*)((char*)d_ws + (size_t)B_N * ROWB);       // 32 KB
  float* T01 = Z + B_N;                                        // 64 KB
  float* D = T01 + 2 * B_N;                                    // 32 KB

  norm_kernel<<<B_N / 4, 256, 0, stream>>>(x, fQ, Z);
  sim_kernel<<<dim3(64, 8), 256, 0, stream>>>(fQ, Z, T01, D);
  finalize_kernel<<<1, 1024, 0, stream>>>(Z, T01, D, ids, anchor, out);
}

// Round 14
// 104.415 us; speedup vs baseline: 1.2948x; 1.0826x over previous
//
#include <hip/hip_runtime.h>

// ---------------------------------------------------------------------------
// VisualContrastiveLoss on MI355X
// loss = C + mean_i log(Z_i) - mean_i sim[i, lab_i],  C = 1/0.07
//   Z_i = sum_j exp(sim_ij - C)  (fixed shift: dots bounded by 1)
//   sim = (f f^T)/0.07, f = row-normalized visual_feat
// R14: SYMMETRY — sim_ij = sim_ji, compute only tiles J >= I (2080/4096).
//     Off-diag tile (I,J): row-sums -> Z[I-band], col-sums -> Z[J-band]
//     (transpose contribution). Diag tile: row-sums only (block holds both
//     triangles). T01 = sim[0,c], sim[1,c] captured from rows 0,1 of the
//     I=0 band. D from diag tiles. Balance: grid (32,16); by<8 -> I=bx
//     (heavy), by>=8 -> I=63-bx (light); blocks c,c+256 pair to ~8.1
//     tiles/CU. Kept from R13 (45.9us): A staged once (h() zero-conflict
//     granule layout), B per kk via global_load_lds, FragU b128 frag loads,
//     raw v_exp_f32, unroll-1, 3-kernel structure.
// ---------------------------------------------------------------------------

typedef int i32x8 __attribute__((ext_vector_type(8)));
typedef float f32x4 __attribute__((ext_vector_type(4)));

#define B_N 8192
#define D_K 512
#define ROWB 512  // bytes per fp8 row
#define INVT 14.285714285714286f
// (1/0.07) * log2(e)
#define SCALE_LOG2 20.609929155556622f

#if defined(__has_builtin) && __has_builtin(__builtin_amdgcn_exp2f)
#define FAST_EXP2(x) __builtin_amdgcn_exp2f(x)
#else
#define FAST_EXP2(x) exp2f(x)
#endif

union FragU {
  int4 h[2];
  i32x8 v;
};

static __device__ __forceinline__ void load16_to_lds(const void* g, void* l) {
  __builtin_amdgcn_global_load_lds(
      (const __attribute__((address_space(1))) unsigned int*)g,
      (__attribute__((address_space(3))) unsigned int*)l, 16, 0, 0);
}

// ---- K1: 4 waves/block, one wave per row; normalize fp32 -> fp8 e4m3 --------
// Also zeroes Z (ws is poisoned before every launch).
__global__ __launch_bounds__(256)
void norm_kernel(const float* __restrict__ x,
                 unsigned char* __restrict__ fQ,
                 float* __restrict__ Z) {
  const int row = blockIdx.x * 4 + (threadIdx.x >> 6);
  const int lane = threadIdx.x & 63;
  const float4* xr = (const float4*)(x + (size_t)row * D_K);
  float4 a = xr[2 * lane];
  float4 b = xr[2 * lane + 1];
  float s = a.x * a.x + a.y * a.y + a.z * a.z + a.w * a.w +
            b.x * b.x + b.y * b.y + b.z * b.z + b.w * b.w;
#pragma unroll
  for (int off = 1; off < 64; off <<= 1) s += __shfl_xor(s, off);
  const float inv = 1.0f / fmaxf(sqrtf(s), 1e-12f);
  int lo = 0, hi = 0;
  lo = __builtin_amdgcn_cvt_pk_fp8_f32(a.x * inv, a.y * inv, lo, false);
  lo = __builtin_amdgcn_cvt_pk_fp8_f32(a.z * inv, a.w * inv, lo, true);
  hi = __builtin_amdgcn_cvt_pk_fp8_f32(b.x * inv, b.y * inv, hi, false);
  hi = __builtin_amdgcn_cvt_pk_fp8_f32(b.z * inv, b.w * inv, hi, true);
  int2 p; p.x = lo; p.y = hi;
  ((int2*)(fQ + (size_t)row * ROWB))[lane] = p;
  if (lane == 0) Z[row] = 0.0f;
}

// ---- K2: upper-triangular fp8 similarity + softmax-denominator --------------
// grid (32, 16): by<8 -> row band I=bx; by>=8 -> I=63-bx. Tile cols
// J in {J >= I, J == (by&7) mod 8}. 4 waves 2x2; wave owns 64x64 C via 4x4
// frags of 16x16x128 MX-fp8 MFMA (scale=1). A (128 rows x full K) staged
// once into 4 chunk-planes; B staged per kk. Granule layout per 128B chunk:
// slot s of row r holds global granule h(s^(r&7)), h(u)=2(u&3)+(u>>2);
// frag reads at slots (q)^swz,(q+4)^swz -> granules 2q,2q+1, zero conflicts.
__global__ __launch_bounds__(256, 2)
void sim_kernel(const unsigned char* __restrict__ fQ,
                float* __restrict__ Z, float* __restrict__ T01,
                float* __restrict__ D) {
  __shared__ unsigned char ldsA[4][128 * 128];  // 64 KB: full K, 4 chunk-planes
  __shared__ unsigned char ldsB[128 * 128];     // 16 KB

  const int tid = threadIdx.x;
  const int lane = tid & 63;
  const int w = tid >> 6;
  const int wm = w & 1;       // wave row strip (0/1) -> rows wm*64..
  const int wn = w >> 1;      // wave col strip (0/1) -> cols wn*64..
  const int bx = blockIdx.x, by = blockIdx.y;
  const int b = by & 7;
  const int I = (by < 8) ? bx : (63 - bx);    // row band index
  const int Jfirst = I + ((b - I) & 7);       // first J >= I with J==b (mod 8)
  if (Jfirst > 63) return;                    // no tiles for this block
  const int I0 = I * 128;

  // staging lane geometry: 8 rows x 8 slots(16B) per instruction.
  const int srow = lane >> 3;                 // 0..7
  const int sb = lane & 7;                    // dest slot
  const int su = sb ^ srow;
  const int sg = 2 * (su & 3) + (su >> 2);    // source granule
  const size_t sOff = (size_t)srow * ROWB + sg * 16;  // bytes

  // fragment-read lane geometry
  const int fr = lane & 15;   // M/N index within 16
  const int q = lane >> 4;    // quad -> k chunk of 32B
  const int swz = fr & 7;     // row&7 of the frag row

  // precomputed LDS frag base offsets (byte addresses)
  const int raRow = (wm * 64 + fr) * 128;
  const unsigned char* rbBase = ldsB + (wn * 64 + fr) * 128;
  const int off0 = (q ^ swz) * 16;        // slot holding granule 2q
  const int off1 = ((q + 4) ^ swz) * 16;  // slot holding granule 2q+1

  // ---- stage A once: wave w stages rows w*32..+31, all 4 K-chunks ----------
#pragma unroll
  for (int kk = 0; kk < 4; ++kk) {
    const unsigned char* gA = fQ + (size_t)(I0 + w * 32) * ROWB + kk * 128 + sOff;
    unsigned char* lA = ldsA[kk] + (w * 32) * 128;
#pragma unroll
    for (int rr = 0; rr < 32; rr += 8)
      load16_to_lds(gA + (size_t)rr * ROWB, lA + rr * 128);
  }
  // (first __syncthreads inside the kk loop below covers A readiness)

  float Zp[4][4];
#pragma unroll
  for (int m = 0; m < 4; ++m)
#pragma unroll
    for (int r = 0; r < 4; ++r) Zp[m][r] = 0.0f;

#pragma unroll 1
  for (int J = Jfirst; J < 64; J += 8) {
    const int J0 = J * 128;
    f32x4 acc[4][4];
#pragma unroll
    for (int m = 0; m < 4; ++m)
#pragma unroll
      for (int n = 0; n < 4; ++n) acc[m][n] = (f32x4){0.f, 0.f, 0.f, 0.f};

#pragma unroll 1
    for (int kk = 0; kk < 4; ++kk) {
      const int k0 = kk * 128;  // byte offset into row
      {  // B: 128 rows, wave stages rows w*32..+31 (4 instrs)
        const unsigned char* gB = fQ + (size_t)(J0 + w * 32) * ROWB + k0 + sOff;
        unsigned char* lB = ldsB + (w * 32) * 128;
#pragma unroll
        for (int rr = 0; rr < 32; rr += 8)
          load16_to_lds(gB + (size_t)rr * ROWB, lB + rr * 128);
      }
      __syncthreads();

      const unsigned char* raBase = ldsA[kk] + raRow;
      i32x8 bv[4];
#pragma unroll
      for (int n = 0; n < 4; ++n) {
        const unsigned char* rb = rbBase + n * 16 * 128;
        FragU u;
        u.h[0] = *(const int4*)(rb + off0);
        u.h[1] = *(const int4*)(rb + off1);
        bv[n] = u.v;
      }
#pragma unroll
      for (int mh = 0; mh < 2; ++mh) {  // m-split: av[2] live, not av[4]
        i32x8 av[2];
#pragma unroll
        for (int m = 0; m < 2; ++m) {
          const unsigned char* ra = raBase + (mh * 2 + m) * 16 * 128;
          FragU u;
          u.h[0] = *(const int4*)(ra + off0);
          u.h[1] = *(const int4*)(ra + off1);
          av[m] = u.v;
        }
#pragma unroll
        for (int m = 0; m < 2; ++m)
#pragma unroll
          for (int n = 0; n < 4; ++n)
            acc[mh * 2 + m][n] = __builtin_amdgcn_mfma_scale_f32_16x16x128_f8f6f4(
                av[m], bv[n], acc[mh * 2 + m][n], 0, 0, 0, 127, 0, 127);
      }
      __syncthreads();
    }

    // T01: sim[0,c], sim[1,c] from rows 0,1 (band I==0 only; rows 0,1 live
    // in wm==0, frag m=0, q==0, r in {0,1}; col c = J0 + wn*64 + n*16 + fr)
    if (I == 0 && wm == 0) {
      if (q == 0) {
#pragma unroll
        for (int n = 0; n < 4; ++n) {
          const int col = J0 + wn * 64 + n * 16 + fr;
          T01[col * 2 + 0] = acc[0][n][0] * INVT;
          T01[col * 2 + 1] = acc[0][n][1] * INVT;
        }
      }
    }

    // D: diagonal dots, from the diagonal tile only
    if (J == I) {
#pragma unroll
      for (int m = 0; m < 4; ++m)
#pragma unroll
        for (int n = 0; n < 4; ++n) {
          const int col = J0 + wn * 64 + n * 16 + fr;
#pragma unroll
          for (int r = 0; r < 4; ++r) {
            const int row = I0 + wm * 64 + m * 16 + q * 4 + r;
            if (row == col) D[row] = acc[m][n][r];
          }
        }
    }

    // Z: row partials always (covers this tile's rows); column sums for
    // off-diag tiles (transpose contribution to Z[J-band]).
    const bool offd = (J != I);
#pragma unroll
    for (int n = 0; n < 4; ++n) {
      float cs = 0.0f;
#pragma unroll
      for (int m = 0; m < 4; ++m)
#pragma unroll
        for (int r = 0; r < 4; ++r) {
          const float e = FAST_EXP2((acc[m][n][r] - 1.0f) * SCALE_LOG2);
          Zp[m][r] += e;
          cs += e;
        }
      if (offd) {
        cs += __shfl_xor(cs, 16);
        cs += __shfl_xor(cs, 32);
        if (q == 0) atomicAdd(&Z[J0 + wn * 64 + n * 16 + fr], cs);
      }
    }
  }

  // row sums: reduce Zp across the 16 col-lanes, then atomicAdd
#pragma unroll
  for (int m = 0; m < 4; ++m)
#pragma unroll
    for (int r = 0; r < 4; ++r) {
      float v = Zp[m][r];
      v += __shfl_xor(v, 1);
      v += __shfl_xor(v, 2);
      v += __shfl_xor(v, 4);
      v += __shfl_xor(v, 8);
      if (fr == 0) atomicAdd(&Z[I0 + wm * 64 + m * 16 + q * 4 + r], v);
    }
}

// ---- K3: labels + exact-diagonal fixup + final loss reduction ---------------
// 1024 threads, 8 rows each, all loads batched/independent.
__global__ __launch_bounds__(1024)
void finalize_kernel(const float* __restrict__ Z,
                     const float* __restrict__ T01,
                     const float* __restrict__ D,
                     const int* __restrict__ ids,
                     const int* __restrict__ anchor,
                     float* __restrict__ out) {
  __shared__ float red[1024];
  const int t = threadIdx.x;
  const int anchor_id = ids[anchor[0]];
  const int sameLast = (ids[B_N - 1] == anchor_id);
  const int samePrev = (ids[B_N - 2] == anchor_id);
  int i[8], id[8];
  float z[8], d[8], t0[8], t1[8];
#pragma unroll
  for (int u = 0; u < 8; ++u) {
    i[u] = u * 1024 + t;
    z[u] = Z[i[u]];
    d[u] = D[i[u]];
    t0[u] = T01[i[u] * 2 + 0];
    t1[u] = T01[i[u] * 2 + 1];
    id[u] = ids[i[u]];
  }
  float sum = 0.0f;
#pragma unroll
  for (int u = 0; u < 8; ++u) {
    const int same_i = (id[u] == anchor_id);
    const int lab =
        (i[u] < B_N - 1) ? (same_i & sameLast) : (sameLast & samePrev);
    const float tt = lab ? t1[u] : t0[u];
    // replace quantized diag contribution with the exact value exp(0)=1
    const float Zc = z[u] - FAST_EXP2((d[u] - 1.0f) * SCALE_LOG2) + 1.0f;
    sum += tt - (INVT + logf(Zc));
  }
  red[t] = sum;
  __syncthreads();
  for (int off = 512; off > 0; off >>= 1) {
    if (t < off) red[t] += red[t + off];
    __syncthreads();
  }
  if (t == 0) out[0] = -red[0] / (float)B_N;
}

// ---------------------------------------------------------------------------
extern "C" void kernel_launch(void* const* d_in, const int* in_sizes, int n_in,
                              void* d_out, int out_size, void* d_ws, size_t ws_size,
                              hipStream_t stream) {
  const float* x = (const float*)d_in[0];
  const int* ids = (const int*)d_in[1];
  const int* anchor = (const int*)d_in[2];
  float* out = (float*)d_out;

  unsigned char* fQ = (unsigned char*)d_ws;                    // 4 MB fp8
  float* Z = (float*)((char*)d_ws + (size_t)B_N * ROWB);       // 32 KB
  float* T01 = Z + B_N;                                        // 64 KB
  float* D = T01 + 2 * B_N;                                    // 32 KB

  norm_kernel<<<B_N / 4, 256, 0, stream>>>(x, fQ, Z);
  sim_kernel<<<dim3(32, 16), 256, 0, stream>>>(fQ, Z, T01, D);
  finalize_kernel<<<1, 1024, 0, stream>>>(Z, T01, D, ids, anchor, out);
}